// Round 5
// baseline (38997.870 us; speedup 1.0000x reference)
//
#include <hip/hip_runtime.h>

constexpr int TT   = 2048;  // timesteps
constexpr int NB   = 128;   // batch
constexpr int NI   = 64;    // input size
constexpr int NH   = 256;   // hidden
constexpr int NGRP = 128;   // WGs per layer
constexpr int NWG  = 256;
constexpr int NTHR = 512;
constexpr int R0   = 8;     // h0 ring slots (layer 0 may run <=7 ahead)
constexpr int R1   = 16;    // h1 ring slots
constexpr int HLAG = 8;     // head lag: at layer-0 step s, head for u = s-8
constexpr int SLOT = (NH / 2) * NB;  // dwords per packed-bf16 h slot (64 KB)

// Per-WG progress arrays (plain stores, no RMW). prog[g] = (completed steps)+1.
// Zero at load; reset at kernel end behind gridbar -> graph-replay safe.
__device__ __align__(256) unsigned g_p0[128];   // layer-0 progress
__device__ __align__(256) unsigned g_p1[128];   // layer-1 progress
__device__ unsigned g_cnt = 0, g_gen = 0;       // end-barrier state only

__device__ __forceinline__ float sigm(float v) { return 1.0f / (1.0f + __expf(-v)); }
__device__ __forceinline__ float tanhfast(float v) {
    float e = __expf(2.0f * v);
    return 1.0f - 2.0f / (e + 1.0f);
}
__device__ __forceinline__ float asfl(unsigned u) { return __uint_as_float(u); }
__device__ __forceinline__ unsigned f2bf(float f) {   // RNE float->bf16 bits
    unsigned u = __float_as_uint(f);
    return (u + 0x7fffu + ((u >> 16) & 1u)) >> 16;
}

// LLC-coherent (agent-scope relaxed) accessors for cross-WG data.
__device__ __forceinline__ unsigned long long ldq(const unsigned* p) {
    return __hip_atomic_load((const unsigned long long*)p, __ATOMIC_RELAXED,
                             __HIP_MEMORY_SCOPE_AGENT);
}
__device__ __forceinline__ unsigned ldd(const unsigned* p) {
    return __hip_atomic_load(p, __ATOMIC_RELAXED, __HIP_MEMORY_SCOPE_AGENT);
}
__device__ __forceinline__ void std_(unsigned* p, unsigned v) {
    __hip_atomic_store(p, v, __ATOMIC_RELAXED, __HIP_MEMORY_SCOPE_AGENT);
}

// Wave 0 polls ALL 128 entries of both progress arrays in parallel:
// lane l checks prog0[2l..2l+1] and prog1[2l..2l+1]; exit when every
// entry meets its target (need==0 -> unconstrained, always true).
__device__ __forceinline__ void pollall(unsigned n0, unsigned n1, int lane) {
    const unsigned* p0 = &g_p0[lane << 1];
    const unsigned* p1 = &g_p1[lane << 1];
    for (;;) {
        unsigned long long a = ldq(p0);
        unsigned long long b = ldq(p1);
        bool ok = ((unsigned)a >= n0) && ((unsigned)(a >> 32) >= n0) &&
                  ((unsigned)b >= n1) && ((unsigned)(b >> 32) >= n1);
        if (__all(ok)) return;
        __builtin_amdgcn_s_sleep(1);
    }
}

// Counter barrier, ONLY for the end-of-kernel reset protocol.
__device__ __forceinline__ void gridbar(unsigned k, bool last) {
    __syncthreads();
    if (threadIdx.x == 0) {
        __threadfence();
        unsigned a = __hip_atomic_fetch_add(&g_cnt, 1u, __ATOMIC_ACQ_REL,
                                            __HIP_MEMORY_SCOPE_AGENT);
        if (a == k * NWG - 1u) {
            if (last) {
                __hip_atomic_store(&g_cnt, 0u, __ATOMIC_RELAXED, __HIP_MEMORY_SCOPE_AGENT);
                __hip_atomic_store(&g_gen, 0u, __ATOMIC_RELEASE, __HIP_MEMORY_SCOPE_AGENT);
            } else {
                __hip_atomic_store(&g_gen, k, __ATOMIC_RELEASE, __HIP_MEMORY_SCOPE_AGENT);
            }
        } else if (!last) {
            while (__hip_atomic_load(&g_gen, __ATOMIC_RELAXED,
                                     __HIP_MEMORY_SCOPE_AGENT) < k)
                __builtin_amdgcn_s_sleep(1);
        }
        __threadfence();
    }
    __syncthreads();
}

// Weight loads: 2 adjacent j columns (jj, jj+1) x 4 gates x 4 k.
// Wave-uniform addresses -> scalar(SMEM) loads, cache-resident.
#define LOADWJ(W, K, kk, jj)                                                       \
    float4 w00 = *(const float4*)((W) + (size_t)(0 * NH + (jj)    ) * (K) + (kk)); \
    float4 w01 = *(const float4*)((W) + (size_t)(1 * NH + (jj)    ) * (K) + (kk)); \
    float4 w02 = *(const float4*)((W) + (size_t)(2 * NH + (jj)    ) * (K) + (kk)); \
    float4 w03 = *(const float4*)((W) + (size_t)(3 * NH + (jj)    ) * (K) + (kk)); \
    float4 w10 = *(const float4*)((W) + (size_t)(0 * NH + (jj) + 1) * (K) + (kk)); \
    float4 w11 = *(const float4*)((W) + (size_t)(1 * NH + (jj) + 1) * (K) + (kk)); \
    float4 w12 = *(const float4*)((W) + (size_t)(2 * NH + (jj) + 1) * (K) + (kk)); \
    float4 w13 = *(const float4*)((W) + (size_t)(3 * NH + (jj) + 1) * (K) + (kk));

// One k value x one batch column x 8 weight rows (2 j x 4 gates).
// A[0..3] = gates(i,f,g,o) of col jj; A[4..7] = col jj+1.
#define STEP1(Q, H, A)                                     \
    (A)[0] += w00.Q * (H); (A)[1] += w01.Q * (H);          \
    (A)[2] += w02.Q * (H); (A)[3] += w03.Q * (H);          \
    (A)[4] += w10.Q * (H); (A)[5] += w11.Q * (H);          \
    (A)[6] += w12.Q * (H); (A)[7] += w13.Q * (H);

// Partial dot over a 64-long k slice of bf16 h packed [k/2][b][2], for ONE
// batch column (col) and FOUR j outputs (j0..j0+3, 16 weight rows).
// acc[0..7] = j0,j0+1 gates; acc[8..15] = j0+2,j0+3 gates.
__device__ __forceinline__ void partH4(const float* __restrict__ W, int j0,
                                       int kbase,
                                       const unsigned* __restrict__ hd,
                                       int col, float* acc) {
    const unsigned* hp = hd + (size_t)(kbase >> 1) * NB + col;
    #pragma unroll 4
    for (int i = 0; i < 16; ++i) {
        const int kk = kbase + (i << 2);
        unsigned d0 = ldd(hp + (size_t)(2 * i) * NB);       // k = kk, kk+1
        unsigned d1 = ldd(hp + (size_t)(2 * i + 1) * NB);   // k = kk+2, kk+3
        float hx = asfl(d0 << 16), hy = asfl(d0 & 0xffff0000u);
        float hz = asfl(d1 << 16), hw = asfl(d1 & 0xffff0000u);
        {
            LOADWJ(W, NH, kk, j0)
            STEP1(x, hx, acc) STEP1(y, hy, acc)
            STEP1(z, hz, acc) STEP1(w, hw, acc)
        }
        {
            LOADWJ(W, NH, kk, j0 + 2)
            STEP1(x, hx, acc + 8) STEP1(y, hy, acc + 8)
            STEP1(z, hz, acc + 8) STEP1(w, hw, acc + 8)
        }
    }
}

// Partial dot over a 16-long k slice of x [b][k] fp32, one batch column.
__device__ __forceinline__ void partX4(const float* __restrict__ W, int j0,
                                       int k0, const float* __restrict__ xp,
                                       float* acc) {
    #pragma unroll
    for (int i4 = 0; i4 < 4; ++i4) {
        const int kk = k0 + (i4 << 2);
        float4 xv = *(const float4*)(xp + kk);
        {
            LOADWJ(W, NI, kk, j0)
            STEP1(x, xv.x, acc) STEP1(y, xv.y, acc)
            STEP1(z, xv.z, acc) STEP1(w, xv.w, acc)
        }
        {
            LOADWJ(W, NI, kk, j0 + 2)
            STEP1(x, xv.x, acc + 8) STEP1(y, xv.y, acc + 8)
            STEP1(z, xv.z, acc + 8) STEP1(w, xv.w, acc + 8)
        }
    }
}

// Grid: 256 WGs x 512 thr, 1 WG/CU. gid<128: layer 0 (+head), else layer 1.
// 2D partition per layer: WG g -> (bg = g>>6, jg = g&63): 64 batch cols
// (b0 = bg*64) x 4 j outputs (j0 = jg*4). Halves the coherent h-broadcast
// (each WG reads h only for its 64 batches) while doubling FLOPs per
// coherent byte. Waves 0-3: Whh·h (64 k each); waves 4-7: Wih·x (L0) or
// Wih1·h0 (L1). Each lane owns ONE batch col, acc = 4 j x 4 gates.
// Partials meet in LDS zp4[32][64]; combine threads (tid<128 = 64 b x 2
// j-pairs) do gates for 2 j and store one packed bf16 dword. c state in
// registers for all 2048 steps. h ring layout UNCHANGED: [k/2][128 b].
__global__ void __launch_bounds__(NTHR, 2) lstm2(
    const float* __restrict__ x,
    const float* __restrict__ h0in, const float* __restrict__ c0in,
    const float* __restrict__ Wih0, const float* __restrict__ Whh0,
    const float* __restrict__ bih0, const float* __restrict__ bhh0,
    const float* __restrict__ Wih1, const float* __restrict__ Whh1,
    const float* __restrict__ bih1, const float* __restrict__ bhh1,
    const float* __restrict__ Wlin, const float* __restrict__ blin,
    float* __restrict__ out,
    unsigned* __restrict__ h0d, unsigned* __restrict__ h1d)
{
    __shared__ __align__(16) float4 zp4[32 * 64];   // [wv*4+jl][b_local], 32 KB
    __shared__ float red[4];
    __shared__ unsigned go_w;

    const int tid  = threadIdx.x;
    const int gid  = blockIdx.x;
    const bool is1 = gid >= NGRP;
    const int g    = is1 ? gid - NGRP : gid;
    const int jg   = g & 63;
    const int j0   = jg * 4;
    const int b0   = (g >> 6) * 64;
    const int lane = tid & 63;
    const int wv   = __builtin_amdgcn_readfirstlane(tid >> 6);

    unsigned* ownp = is1 ? g_p1 : g_p0;

    // ---- init: biases + c state + h(-1) publish (packed bf16) ----
    // Combine thread ct = tid<128: b_local = ct>>1, j-pair jp = ct&1
    // -> j columns jc = j0+2jp, jc+1; global batch col bcol = b0 + b_local.
    float4 bsA = make_float4(0, 0, 0, 0), bsB = bsA;
    float cA = 0.f, cB = 0.f;
    if (tid < 128) {
        const int bcol = b0 + (tid >> 1);
        const int jp   = tid & 1;
        const int jc   = j0 + 2 * jp;
        const float* bi = is1 ? bih1 : bih0;
        const float* bh = is1 ? bhh1 : bhh0;
        bsA.x = bi[0 * NH + jc] + bh[0 * NH + jc];
        bsA.y = bi[1 * NH + jc] + bh[1 * NH + jc];
        bsA.z = bi[2 * NH + jc] + bh[2 * NH + jc];
        bsA.w = bi[3 * NH + jc] + bh[3 * NH + jc];
        bsB.x = bi[0 * NH + jc + 1] + bh[0 * NH + jc + 1];
        bsB.y = bi[1 * NH + jc + 1] + bh[1 * NH + jc + 1];
        bsB.z = bi[2 * NH + jc + 1] + bh[2 * NH + jc + 1];
        bsB.w = bi[3 * NH + jc + 1] + bh[3 * NH + jc + 1];
        const float* cbase = c0in + (is1 ? 1 : 0) * NB * NH + (size_t)bcol * NH + jc;
        cA = cbase[0]; cB = cbase[1];
        const float* hbase = h0in + (is1 ? 1 : 0) * NB * NH + (size_t)bcol * NH + jc;
        unsigned d = (f2bf(hbase[1]) << 16) | f2bf(hbase[0]);
        unsigned* hT = is1 ? h1d : h0d;
        const int islot = is1 ? (R1 - 1) : (R0 - 1);
        std_(hT + (size_t)islot * SLOT + (size_t)((j0 >> 1) + jp) * NB + bcol, d);
    }
    if (tid == 0) go_w = 0;
    const float blv = blin[0];
    asm volatile("s_waitcnt vmcnt(0)" ::: "memory");
    __syncthreads();
    if (tid == 0) std_(&ownp[g], 1u);   // progress 1 per WG after init

    if (!is1) {
        // ================= layer 0 (+ head, lag HLAG) =================
        for (int s = 0; s < TT + HLAG; ++s) {
            const unsigned tgt = (unsigned)(s + 1);
            unsigned need0 = (s < TT) ? (unsigned)(s + 1) : 0u;
            unsigned need1 = (s >= R0) ? (unsigned)(s - R0 + 2) : 0u;
            if (wv == 0) {
                pollall(need0, need1, lane);
                if (lane == 0)
                    __hip_atomic_store(&go_w, tgt, __ATOMIC_RELAXED,
                                       __HIP_MEMORY_SCOPE_WORKGROUP);
            } else {
                while (__hip_atomic_load(&go_w, __ATOMIC_RELAXED,
                                         __HIP_MEMORY_SCOPE_WORKGROUP) < tgt) {}
            }

            if (s < TT) {
                float acc[16] = {0,0,0,0,0,0,0,0,0,0,0,0,0,0,0,0};
                if (wv < 4)
                    partH4(Whh0, j0, wv * 64,
                           h0d + (size_t)((s + R0 - 1) & (R0 - 1)) * SLOT,
                           b0 + lane, acc);
                else
                    partX4(Wih0, j0, (wv - 4) * 16,
                           x + (size_t)s * NB * NI + (size_t)(b0 + lane) * NI, acc);
                const int zb = (wv << 2) * 64 + lane;
                zp4[zb]       = make_float4(acc[0],  acc[1],  acc[2],  acc[3]);
                zp4[zb + 64]  = make_float4(acc[4],  acc[5],  acc[6],  acc[7]);
                zp4[zb + 128] = make_float4(acc[8],  acc[9],  acc[10], acc[11]);
                zp4[zb + 192] = make_float4(acc[12], acc[13], acc[14], acc[15]);
            }
            if (s >= HLAG && tid >= 256) {          // head partial for u = s-HLAG
                const int u = s - HLAG;
                const int k = tid - 256;
                unsigned d = ldd(h1d + (size_t)(u & (R1 - 1)) * SLOT
                                 + (size_t)(k >> 1) * NB + g);
                float hv = (k & 1) ? asfl(d & 0xffff0000u) : asfl(d << 16);
                float p = Wlin[k] * hv;
                #pragma unroll
                for (int off = 32; off; off >>= 1) p += __shfl_down(p, off);
                if (lane == 0) red[wv - 4] = p;
            }
            __syncthreads();

            if (s < TT && tid < 128) {              // combine 2 j, store packed
                const int bl = tid >> 1, jp = tid & 1;
                float4 zA = bsA, zB = bsB;
                #pragma unroll
                for (int q = 0; q < 8; ++q) {
                    float4 a = zp4[((q << 2) + 2 * jp) * 64 + bl];
                    float4 b = zp4[((q << 2) + 2 * jp + 1) * 64 + bl];
                    zA.x += a.x; zA.y += a.y; zA.z += a.z; zA.w += a.w;
                    zB.x += b.x; zB.y += b.y; zB.z += b.z; zB.w += b.w;
                }
                float iA = sigm(zA.x), fA = sigm(zA.y), gA = tanhfast(zA.z), oA = sigm(zA.w);
                cA = fA * cA + iA * gA;
                float hA = oA * tanhfast(cA);
                float iB = sigm(zB.x), fB = sigm(zB.y), gB = tanhfast(zB.z), oB = sigm(zB.w);
                cB = fB * cB + iB * gB;
                float hB = oB * tanhfast(cB);
                unsigned d = (f2bf(hB) << 16) | f2bf(hA);
                std_(h0d + (size_t)(s & (R0 - 1)) * SLOT
                     + (size_t)((j0 >> 1) + jp) * NB + (b0 + bl), d);
            }
            if (s >= HLAG && tid == 256)
                out[(size_t)(s - HLAG) * NB + g] = red[0] + red[1] + red[2] + red[3] + blv;

            asm volatile("s_waitcnt vmcnt(0)" ::: "memory");
            __syncthreads();
            if (s < TT && tid == 0) std_(&g_p0[g], (unsigned)(s + 2));
        }
    } else {
        // ================= layer 1 =================
        for (int t = 0; t < TT; ++t) {
            const unsigned tgt = (unsigned)(t + 1);
            unsigned need0 = (unsigned)(t + 2);   // h0(t) ready
            unsigned need1 = (unsigned)(t + 1);   // h1(t-1) ready
            if (wv == 0) {
                pollall(need0, need1, lane);
                if (lane == 0)
                    __hip_atomic_store(&go_w, tgt, __ATOMIC_RELAXED,
                                       __HIP_MEMORY_SCOPE_WORKGROUP);
            } else {
                while (__hip_atomic_load(&go_w, __ATOMIC_RELAXED,
                                         __HIP_MEMORY_SCOPE_WORKGROUP) < tgt) {}
            }

            float acc[16] = {0,0,0,0,0,0,0,0,0,0,0,0,0,0,0,0};
            if (wv < 4)
                partH4(Wih1, j0, wv * 64,
                       h0d + (size_t)(t & (R0 - 1)) * SLOT, b0 + lane, acc);
            else
                partH4(Whh1, j0, (wv - 4) * 64,
                       h1d + (size_t)((t + R1 - 1) & (R1 - 1)) * SLOT, b0 + lane, acc);
            const int zb = (wv << 2) * 64 + lane;
            zp4[zb]       = make_float4(acc[0],  acc[1],  acc[2],  acc[3]);
            zp4[zb + 64]  = make_float4(acc[4],  acc[5],  acc[6],  acc[7]);
            zp4[zb + 128] = make_float4(acc[8],  acc[9],  acc[10], acc[11]);
            zp4[zb + 192] = make_float4(acc[12], acc[13], acc[14], acc[15]);
            __syncthreads();

            if (tid < 128) {
                const int bl = tid >> 1, jp = tid & 1;
                float4 zA = bsA, zB = bsB;
                #pragma unroll
                for (int q = 0; q < 8; ++q) {
                    float4 a = zp4[((q << 2) + 2 * jp) * 64 + bl];
                    float4 b = zp4[((q << 2) + 2 * jp + 1) * 64 + bl];
                    zA.x += a.x; zA.y += a.y; zA.z += a.z; zA.w += a.w;
                    zB.x += b.x; zB.y += b.y; zB.z += b.z; zB.w += b.w;
                }
                float iA = sigm(zA.x), fA = sigm(zA.y), gA = tanhfast(zA.z), oA = sigm(zA.w);
                cA = fA * cA + iA * gA;
                float hA = oA * tanhfast(cA);
                float iB = sigm(zB.x), fB = sigm(zB.y), gB = tanhfast(zB.z), oB = sigm(zB.w);
                cB = fB * cB + iB * gB;
                float hB = oB * tanhfast(cB);
                unsigned d = (f2bf(hB) << 16) | f2bf(hA);
                std_(h1d + (size_t)(t & (R1 - 1)) * SLOT
                     + (size_t)((j0 >> 1) + jp) * NB + (b0 + bl), d);
            }
            asm volatile("s_waitcnt vmcnt(0)" ::: "memory");
            __syncthreads();
            if (tid == 0) std_(&g_p1[g], (unsigned)(t + 2));
        }
    }

    // ---- end protocol: reset progress behind a real barrier (replay-safe) ----
    gridbar(1, false);
    if (gid == 0 && tid < 128) {
        std_(&g_p0[tid], 0u);
        std_(&g_p1[tid], 0u);
    }
    asm volatile("s_waitcnt vmcnt(0)" ::: "memory");
    gridbar(2, true);
}

extern "C" void kernel_launch(void* const* d_in, const int* in_sizes, int n_in,
                              void* d_out, int out_size, void* d_ws, size_t ws_size,
                              hipStream_t stream)
{
    const float* x    = (const float*)d_in[0];
    const float* h0in = (const float*)d_in[1];
    const float* c0in = (const float*)d_in[2];
    const float* Wih0 = (const float*)d_in[3];
    const float* Whh0 = (const float*)d_in[4];
    const float* bih0 = (const float*)d_in[5];
    const float* bhh0 = (const float*)d_in[6];
    const float* Wih1 = (const float*)d_in[7];
    const float* Whh1 = (const float*)d_in[8];
    const float* bih1 = (const float*)d_in[9];
    const float* bhh1 = (const float*)d_in[10];
    const float* Wlin = (const float*)d_in[11];
    const float* blin = (const float*)d_in[12];
    float* out = (float*)d_out;

    unsigned* h0d = (unsigned*)d_ws;            // [R0][NH/2][NB] packed bf16
    unsigned* h1d = h0d + (size_t)R0 * SLOT;    // [R1][NH/2][NB] packed bf16

    void* args[] = { &x, &h0in, &c0in, &Wih0, &Whh0, &bih0, &bhh0,
                     &Wih1, &Whh1, &bih1, &bhh1, &Wlin, &blin,
                     &out, &h0d, &h1d };
    hipLaunchCooperativeKernel((void*)lstm2, dim3(NWG), dim3(NTHR), args, 0, stream);
}

// Round 6
// 26911.044 us; speedup vs baseline: 1.4491x; 1.4491x over previous
//
#include <hip/hip_runtime.h>

constexpr int TT   = 2048;  // timesteps
constexpr int NB   = 128;   // batch
constexpr int NI   = 64;    // input size
constexpr int NH   = 256;   // hidden
constexpr int NGRP = 128;   // WGs per layer
constexpr int NWG  = 256;
constexpr int NTHR = 512;
constexpr int R0   = 8;     // h0 ring slots (layer 0 may run <=7 ahead)
constexpr int R1   = 16;    // h1 ring slots
constexpr int HLAG = 8;     // head lag: at layer-0 step s, head for u = s-8
constexpr int SLOT = (NH / 2) * NB;  // dwords per packed-bf16 h slot (64 KB)

// Per-WG progress arrays (plain stores, no RMW). prog[g] = (completed steps)+1.
// Zero at load; reset at kernel end behind gridbar -> graph-replay safe.
__device__ __align__(256) unsigned g_p0[128];   // layer-0 progress
__device__ __align__(256) unsigned g_p1[128];   // layer-1 progress
__device__ unsigned g_cnt = 0, g_gen = 0;       // end-barrier state only

__device__ __forceinline__ float sigm(float v) { return 1.0f / (1.0f + __expf(-v)); }
__device__ __forceinline__ float tanhfast(float v) {
    float e = __expf(2.0f * v);
    return 1.0f - 2.0f / (e + 1.0f);
}
__device__ __forceinline__ float asfl(unsigned u) { return __uint_as_float(u); }
__device__ __forceinline__ unsigned f2bf(float f) {   // RNE float->bf16 bits
    unsigned u = __float_as_uint(f);
    return (u + 0x7fffu + ((u >> 16) & 1u)) >> 16;
}

// LLC-coherent (agent-scope relaxed) accessors for cross-WG data.
__device__ __forceinline__ unsigned long long ldq(const unsigned* p) {
    return __hip_atomic_load((const unsigned long long*)p, __ATOMIC_RELAXED,
                             __HIP_MEMORY_SCOPE_AGENT);
}
__device__ __forceinline__ unsigned ldd(const unsigned* p) {
    return __hip_atomic_load(p, __ATOMIC_RELAXED, __HIP_MEMORY_SCOPE_AGENT);
}
__device__ __forceinline__ void std_(unsigned* p, unsigned v) {
    __hip_atomic_store(p, v, __ATOMIC_RELAXED, __HIP_MEMORY_SCOPE_AGENT);
}

// Per-wave subset poll: this wave's k-slice depends on exactly 32 producer
// WGs; poll ONLY their flags. Lanes 32-63 mirror lanes 0-31 (same line).
// Each wave starts computing the moment ITS inputs are ready — no go_w
// relay, no max-over-128-stragglers, and stale-operand waves (Wih1·h0,
// which is ~7 steps old) run during the chain-critical waves' wait.
__device__ __forceinline__ void pollsub(const unsigned* p, unsigned n) {
    const int l = threadIdx.x & 31;
    for (;;) {
        unsigned v = ldd(p + l);
        if (__all(v >= n)) return;
        __builtin_amdgcn_s_sleep(1);
    }
}

// Full-array poll (128 flags, 2 per lane) — used only for the rarely-
// blocking ring/head guards.
__device__ __forceinline__ void poll128(const unsigned* arr, unsigned n) {
    const unsigned* p = arr + ((threadIdx.x & 63) << 1);
    for (;;) {
        unsigned long long a = ldq(p);
        if (__all(((unsigned)a >= n) && ((unsigned)(a >> 32) >= n))) return;
        __builtin_amdgcn_s_sleep(1);
    }
}

// Counter barrier, ONLY for the end-of-kernel reset protocol.
__device__ __forceinline__ void gridbar(unsigned k, bool last) {
    __syncthreads();
    if (threadIdx.x == 0) {
        __threadfence();
        unsigned a = __hip_atomic_fetch_add(&g_cnt, 1u, __ATOMIC_ACQ_REL,
                                            __HIP_MEMORY_SCOPE_AGENT);
        if (a == k * NWG - 1u) {
            if (last) {
                __hip_atomic_store(&g_cnt, 0u, __ATOMIC_RELAXED, __HIP_MEMORY_SCOPE_AGENT);
                __hip_atomic_store(&g_gen, 0u, __ATOMIC_RELEASE, __HIP_MEMORY_SCOPE_AGENT);
            } else {
                __hip_atomic_store(&g_gen, k, __ATOMIC_RELEASE, __HIP_MEMORY_SCOPE_AGENT);
            }
        } else if (!last) {
            while (__hip_atomic_load(&g_gen, __ATOMIC_RELAXED,
                                     __HIP_MEMORY_SCOPE_AGENT) < k)
                __builtin_amdgcn_s_sleep(1);
        }
        __threadfence();
    }
    __syncthreads();
}

// One FMA block: 8 weight rows (2 j x 4 gates) x one k, two b columns.
#define STEPQ(Q, HA, HB)                                   \
    acc[0]  += w00.Q * (HA); acc[1]  += w00.Q * (HB);      \
    acc[2]  += w01.Q * (HA); acc[3]  += w01.Q * (HB);      \
    acc[4]  += w02.Q * (HA); acc[5]  += w02.Q * (HB);      \
    acc[6]  += w03.Q * (HA); acc[7]  += w03.Q * (HB);      \
    acc[8]  += w10.Q * (HA); acc[9]  += w10.Q * (HB);      \
    acc[10] += w11.Q * (HA); acc[11] += w11.Q * (HB);      \
    acc[12] += w12.Q * (HA); acc[13] += w12.Q * (HB);      \
    acc[14] += w13.Q * (HA); acc[15] += w13.Q * (HB);

#define LOADW(W, K, kk)                                                        \
    float4 w00 = *(const float4*)((W) + (size_t)(0 * NH + j0    ) * (K) + (kk)); \
    float4 w01 = *(const float4*)((W) + (size_t)(1 * NH + j0    ) * (K) + (kk)); \
    float4 w02 = *(const float4*)((W) + (size_t)(2 * NH + j0    ) * (K) + (kk)); \
    float4 w03 = *(const float4*)((W) + (size_t)(3 * NH + j0    ) * (K) + (kk)); \
    float4 w10 = *(const float4*)((W) + (size_t)(0 * NH + j0 + 1) * (K) + (kk)); \
    float4 w11 = *(const float4*)((W) + (size_t)(1 * NH + j0 + 1) * (K) + (kk)); \
    float4 w12 = *(const float4*)((W) + (size_t)(2 * NH + j0 + 1) * (K) + (kk)); \
    float4 w13 = *(const float4*)((W) + (size_t)(3 * NH + j0 + 1) * (K) + (kk));

// Partial dot over a 64-long k slice of bf16 h packed [k/2][b][2].
// One dwordx2 = 2 k x 2 b. Weights fp32, L1-resident, wave-uniform rows.
// (R0-verified form: unroll 4, per-iteration ldq — do not touch.)
__device__ __forceinline__ void partH_bf(const float* __restrict__ W, int j0,
                                         int kbase,
                                         const unsigned* __restrict__ hd,
                                         int lane, float* acc) {
    const unsigned* hp = hd + (size_t)(kbase >> 1) * NB + (lane << 1);
    #pragma unroll 4
    for (int i = 0; i < 16; ++i) {
        const int kk = kbase + (i << 2);
        LOADW(W, NH, kk)
        unsigned long long q0 = ldq(hp + (size_t)(2 * i) * NB);
        unsigned long long q1 = ldq(hp + (size_t)(2 * i + 1) * NB);
        unsigned d00 = (unsigned)q0, d01 = (unsigned)(q0 >> 32);
        unsigned d10 = (unsigned)q1, d11 = (unsigned)(q1 >> 32);
        STEPQ(x, asfl(d00 << 16),          asfl(d01 << 16))
        STEPQ(y, asfl(d00 & 0xffff0000u),  asfl(d01 & 0xffff0000u))
        STEPQ(z, asfl(d10 << 16),          asfl(d11 << 16))
        STEPQ(w, asfl(d10 & 0xffff0000u),  asfl(d11 & 0xffff0000u))
    }
}

// Partial dot over a 16-long k slice of x stored [b][k] fp32 (cached loads).
__device__ __forceinline__ void partX(const float* __restrict__ W, int j0,
                                      int k0, const float* __restrict__ xp,
                                      int lane, float* acc) {
    #pragma unroll
    for (int i4 = 0; i4 < 4; ++i4) {
        const int kk = k0 + (i4 << 2);
        LOADW(W, NI, kk)
        float4 xa = *(const float4*)(xp + (size_t)(lane << 1) * NI + kk);
        float4 xb = *(const float4*)(xp + (size_t)((lane << 1) + 1) * NI + kk);
        STEPQ(x, xa.x, xb.x)
        STEPQ(y, xa.y, xb.y)
        STEPQ(z, xa.z, xb.z)
        STEPQ(w, xa.w, xb.w)
    }
}

// Grid: 256 WGs x 512 thr, 1 WG/CU. gid<128: layer 0 (+head), else layer 1.
// WG g owns j0=2g, 2g+1 (8 gate rows) x all 128 b. Waves 0-3: Whh·h (64 k
// each); waves 4-7: Wih·x (L0) or Wih1·h0 (L1). Partials meet in LDS zp4;
// combine threads (tid<128, one per b) do gates for BOTH j and store one
// packed bf16 dword. c state lives in registers for all 2048 steps.
// Synchronization: per-wave subset polls (32 producer flags each).
// Wave w's k-slice [w*64, w*64+64) <-> packed rows [w*32,+32) <-> producer
// WGs of the same indices, since WG g stores row g.
__global__ void __launch_bounds__(NTHR, 2) lstm2(
    const float* __restrict__ x,
    const float* __restrict__ h0in, const float* __restrict__ c0in,
    const float* __restrict__ Wih0, const float* __restrict__ Whh0,
    const float* __restrict__ bih0, const float* __restrict__ bhh0,
    const float* __restrict__ Wih1, const float* __restrict__ Whh1,
    const float* __restrict__ bih1, const float* __restrict__ bhh1,
    const float* __restrict__ Wlin, const float* __restrict__ blin,
    float* __restrict__ out,
    unsigned* __restrict__ h0d, unsigned* __restrict__ h1d)
{
    __shared__ __align__(16) float4 zp4[16 * NB];   // [wv*2+jl][b] gates, 32 KB
    __shared__ float red[4];

    const int tid  = threadIdx.x;
    const int gid  = blockIdx.x;
    const bool is1 = gid >= NGRP;
    const int g    = is1 ? gid - NGRP : gid;
    const int j0   = g * 2;
    const int lane = tid & 63;
    const int wv   = __builtin_amdgcn_readfirstlane(tid >> 6);

    unsigned* ownp = is1 ? g_p1 : g_p0;

    // ---- init: biases + c state + h(-1) publish (packed bf16) ----
    float4 bsA = make_float4(0, 0, 0, 0), bsB = bsA;
    float cA = 0.f, cB = 0.f;
    if (tid < 128) {
        const float* bi = is1 ? bih1 : bih0;
        const float* bh = is1 ? bhh1 : bhh0;
        bsA.x = bi[0 * NH + j0] + bh[0 * NH + j0];
        bsA.y = bi[1 * NH + j0] + bh[1 * NH + j0];
        bsA.z = bi[2 * NH + j0] + bh[2 * NH + j0];
        bsA.w = bi[3 * NH + j0] + bh[3 * NH + j0];
        bsB.x = bi[0 * NH + j0 + 1] + bh[0 * NH + j0 + 1];
        bsB.y = bi[1 * NH + j0 + 1] + bh[1 * NH + j0 + 1];
        bsB.z = bi[2 * NH + j0 + 1] + bh[2 * NH + j0 + 1];
        bsB.w = bi[3 * NH + j0 + 1] + bh[3 * NH + j0 + 1];
        const float* cbase = c0in + (is1 ? 1 : 0) * NB * NH + (size_t)tid * NH + j0;
        cA = cbase[0]; cB = cbase[1];
        const float* hbase = h0in + (is1 ? 1 : 0) * NB * NH + (size_t)tid * NH + j0;
        unsigned d = (f2bf(hbase[1]) << 16) | f2bf(hbase[0]);
        unsigned* hT = is1 ? h1d : h0d;
        const int islot = is1 ? (R1 - 1) : (R0 - 1);
        std_(hT + (size_t)islot * SLOT + (size_t)g * NB + tid, d);
    }
    const float blv = blin[0];
    asm volatile("s_waitcnt vmcnt(0)" ::: "memory");
    __syncthreads();
    if (tid == 0) std_(&ownp[g], 1u);   // progress 1 per WG after init

    if (!is1) {
        // ================= layer 0 (+ head, lag HLAG) =================
        for (int s = 0; s < TT + HLAG; ++s) {
            // Waves 0-3 (Whh0·h0(s-1), the layer-0 chain): wait only on the
            // 32 producers of this wave's k-slice.
            if (s < TT && wv < 4)
                pollsub(&g_p0[wv * 32], (unsigned)(s + 1));
            // Waves 4-7: x needs no wait. For s>=8 the SAME target s-6
            // covers (a) head data h1(s-8) ready and (b) the h0-ring store
            // guard (L1 consumed h0(s-8)); enforced before barrier-1, which
            // orders it before the combine stores.
            if (wv >= 4 && s >= R0)
                poll128(g_p1, (unsigned)(s - R0 + 2));

            if (s < TT) {
                float acc[16] = {0,0,0,0,0,0,0,0,0,0,0,0,0,0,0,0};
                if (wv < 4)
                    partH_bf(Whh0, j0, wv * 64,
                             h0d + (size_t)((s + R0 - 1) & (R0 - 1)) * SLOT, lane, acc);
                else
                    partX(Wih0, j0, (wv - 4) * 16, x + (size_t)s * NB * NI, lane, acc);
                const int base0 = ((wv << 1) + 0) * NB + (lane << 1);
                const int base1 = ((wv << 1) + 1) * NB + (lane << 1);
                zp4[base0]     = make_float4(acc[0],  acc[2],  acc[4],  acc[6]);
                zp4[base0 + 1] = make_float4(acc[1],  acc[3],  acc[5],  acc[7]);
                zp4[base1]     = make_float4(acc[8],  acc[10], acc[12], acc[14]);
                zp4[base1 + 1] = make_float4(acc[9],  acc[11], acc[13], acc[15]);
            }
            if (s >= HLAG && tid >= 256) {          // head partial for u = s-HLAG
                const int u = s - HLAG;
                const int k = tid - 256;
                unsigned d = ldd(h1d + (size_t)(u & (R1 - 1)) * SLOT
                                 + (size_t)(k >> 1) * NB + g);
                float hv = (k & 1) ? asfl(d & 0xffff0000u) : asfl(d << 16);
                float p = Wlin[k] * hv;
                #pragma unroll
                for (int off = 32; off; off >>= 1) p += __shfl_down(p, off);
                if (lane == 0) red[wv - 4] = p;
            }
            __syncthreads();

            if (s < TT && tid < 128) {              // combine both j, store packed
                float4 zA = bsA, zB = bsB;
                #pragma unroll
                for (int q = 0; q < 8; ++q) {
                    float4 a = zp4[(q * 2 + 0) * NB + tid];
                    float4 b = zp4[(q * 2 + 1) * NB + tid];
                    zA.x += a.x; zA.y += a.y; zA.z += a.z; zA.w += a.w;
                    zB.x += b.x; zB.y += b.y; zB.z += b.z; zB.w += b.w;
                }
                float iA = sigm(zA.x), fA = sigm(zA.y), gA = tanhfast(zA.z), oA = sigm(zA.w);
                cA = fA * cA + iA * gA;
                float hA = oA * tanhfast(cA);
                float iB = sigm(zB.x), fB = sigm(zB.y), gB = tanhfast(zB.z), oB = sigm(zB.w);
                cB = fB * cB + iB * gB;
                float hB = oB * tanhfast(cB);
                unsigned d = (f2bf(hB) << 16) | f2bf(hA);
                std_(h0d + (size_t)(s & (R0 - 1)) * SLOT + (size_t)g * NB + tid, d);
            }
            if (s >= HLAG && tid == 256)
                out[(size_t)(s - HLAG) * NB + g] = red[0] + red[1] + red[2] + red[3] + blv;

            asm volatile("s_waitcnt vmcnt(0)" ::: "memory");
            __syncthreads();
            if (s < TT && tid == 0) std_(&g_p0[g], (unsigned)(s + 2));
        }
    } else {
        // ================= layer 1 =================
        for (int t = 0; t < TT; ++t) {
            // Waves 0-3 (Wih1·h0(t)): h0(t) is ~7 steps stale (L0 runs
            // ahead) -> poll almost never spins; these waves compute during
            // the chain waves' wait and park at barrier-1. Jointly they
            // cover all 128 g_p0 >= t+2, which subsumes the h1-ring head
            // guard (needs all g_p0 >= t-6). Waves 4-7 (Whh1·h1(t-1)) are
            // the cross-step chain: subset poll, then compute with the SIMD
            // mostly to themselves.
            if (wv < 4)
                pollsub(&g_p0[wv * 32], (unsigned)(t + 2));
            else
                pollsub(&g_p1[(wv - 4) * 32], (unsigned)(t + 1));

            float acc[16] = {0,0,0,0,0,0,0,0,0,0,0,0,0,0,0,0};
            if (wv < 4)
                partH_bf(Wih1, j0, wv * 64,
                         h0d + (size_t)(t & (R0 - 1)) * SLOT, lane, acc);
            else
                partH_bf(Whh1, j0, (wv - 4) * 64,
                         h1d + (size_t)((t + R1 - 1) & (R1 - 1)) * SLOT, lane, acc);
            const int base0 = ((wv << 1) + 0) * NB + (lane << 1);
            const int base1 = ((wv << 1) + 1) * NB + (lane << 1);
            zp4[base0]     = make_float4(acc[0],  acc[2],  acc[4],  acc[6]);
            zp4[base0 + 1] = make_float4(acc[1],  acc[3],  acc[5],  acc[7]);
            zp4[base1]     = make_float4(acc[8],  acc[10], acc[12], acc[14]);
            zp4[base1 + 1] = make_float4(acc[9],  acc[11], acc[13], acc[15]);
            __syncthreads();

            if (tid < 128) {
                float4 zA = bsA, zB = bsB;
                #pragma unroll
                for (int q = 0; q < 8; ++q) {
                    float4 a = zp4[(q * 2 + 0) * NB + tid];
                    float4 b = zp4[(q * 2 + 1) * NB + tid];
                    zA.x += a.x; zA.y += a.y; zA.z += a.z; zA.w += a.w;
                    zB.x += b.x; zB.y += b.y; zB.z += b.z; zB.w += b.w;
                }
                float iA = sigm(zA.x), fA = sigm(zA.y), gA = tanhfast(zA.z), oA = sigm(zA.w);
                cA = fA * cA + iA * gA;
                float hA = oA * tanhfast(cA);
                float iB = sigm(zB.x), fB = sigm(zB.y), gB = tanhfast(zB.z), oB = sigm(zB.w);
                cB = fB * cB + iB * gB;
                float hB = oB * tanhfast(cB);
                unsigned d = (f2bf(hB) << 16) | f2bf(hA);
                std_(h1d + (size_t)(t & (R1 - 1)) * SLOT + (size_t)g * NB + tid, d);
            }
            asm volatile("s_waitcnt vmcnt(0)" ::: "memory");
            __syncthreads();
            if (tid == 0) std_(&g_p1[g], (unsigned)(t + 2));
        }
    }

    // ---- end protocol: reset progress behind a real barrier (replay-safe) ----
    gridbar(1, false);
    if (gid == 0 && tid < 128) {
        std_(&g_p0[tid], 0u);
        std_(&g_p1[tid], 0u);
    }
    asm volatile("s_waitcnt vmcnt(0)" ::: "memory");
    gridbar(2, true);
}

extern "C" void kernel_launch(void* const* d_in, const int* in_sizes, int n_in,
                              void* d_out, int out_size, void* d_ws, size_t ws_size,
                              hipStream_t stream)
{
    const float* x    = (const float*)d_in[0];
    const float* h0in = (const float*)d_in[1];
    const float* c0in = (const float*)d_in[2];
    const float* Wih0 = (const float*)d_in[3];
    const float* Whh0 = (const float*)d_in[4];
    const float* bih0 = (const float*)d_in[5];
    const float* bhh0 = (const float*)d_in[6];
    const float* Wih1 = (const float*)d_in[7];
    const float* Whh1 = (const float*)d_in[8];
    const float* bih1 = (const float*)d_in[9];
    const float* bhh1 = (const float*)d_in[10];
    const float* Wlin = (const float*)d_in[11];
    const float* blin = (const float*)d_in[12];
    float* out = (float*)d_out;

    unsigned* h0d = (unsigned*)d_ws;            // [R0][NH/2][NB] packed bf16
    unsigned* h1d = h0d + (size_t)R0 * SLOT;    // [R1][NH/2][NB] packed bf16

    void* args[] = { &x, &h0in, &c0in, &Wih0, &Whh0, &bih0, &bhh0,
                     &Wih1, &Whh1, &bih1, &bhh1, &Wlin, &blin,
                     &out, &h0d, &h1d };
    hipLaunchCooperativeKernel((void*)lstm2, dim3(NWG), dim3(NTHR), args, 0, stream);
}

// Round 7
// 20154.454 us; speedup vs baseline: 1.9350x; 1.3352x over previous
//
#include <hip/hip_runtime.h>

constexpr int TT   = 2048;  // timesteps
constexpr int NB   = 128;   // batch
constexpr int NI   = 64;    // input size
constexpr int NH   = 256;   // hidden
constexpr int NGRP = 128;   // WGs per layer
constexpr int NWG  = 256;
constexpr int NTHR = 512;
constexpr int R0   = 8;     // h0 ring slots (layer 0 may run <=7 ahead)
constexpr int R1   = 16;    // h1 ring slots
constexpr int HLAG = 8;     // head lag: at layer-0 step s, head for u = s-8
constexpr int SLOT = (NH / 2) * NB;  // dwords per packed-bf16 h slot (64 KB)

// Aggregated monotone counters (one cacheline apart) + end-barrier state.
// R0-proven minimal-poll protocol: 1 polling wave per WG, 1 address per
// counter. Zero at load; reset at kernel end -> graph-replay safe.
__device__ unsigned g_c[64];          // g_c[0]=layer-0 publishes, g_c[32]=layer-1
__device__ unsigned g_cnt = 0, g_gen = 0;

__device__ __forceinline__ float sigm(float v) { return 1.0f / (1.0f + __expf(-v)); }
__device__ __forceinline__ float tanhfast(float v) {
    float e = __expf(2.0f * v);
    return 1.0f - 2.0f / (e + 1.0f);
}
__device__ __forceinline__ float asfl(unsigned u) { return __uint_as_float(u); }
__device__ __forceinline__ unsigned f2bf(float f) {   // RNE float->bf16 bits
    unsigned u = __float_as_uint(f);
    return (u + 0x7fffu + ((u >> 16) & 1u)) >> 16;
}

// LLC-coherent (agent-scope relaxed) accessors for cross-WG h data.
__device__ __forceinline__ unsigned long long ldq(const unsigned* p) {
    return __hip_atomic_load((const unsigned long long*)p, __ATOMIC_RELAXED,
                             __HIP_MEMORY_SCOPE_AGENT);
}
__device__ __forceinline__ unsigned ldd(const unsigned* p) {
    return __hip_atomic_load(p, __ATOMIC_RELAXED, __HIP_MEMORY_SCOPE_AGENT);
}
__device__ __forceinline__ void std_(unsigned* p, unsigned v) {
    __hip_atomic_store(p, v, __ATOMIC_RELAXED, __HIP_MEMORY_SCOPE_AGENT);
}
__device__ __forceinline__ void bump(unsigned* p) {
    (void)__hip_atomic_fetch_add(p, 1u, __ATOMIC_RELAXED, __HIP_MEMORY_SCOPE_AGENT);
}

// Single-counter poll: all lanes load the same address (1 LLC request per
// iteration per WG) — minimal poll volume, the R0-winning property.
__device__ __forceinline__ void poll1(const unsigned* p, unsigned n) {
    for (;;) {
        unsigned v = ldd(p);
        if (__all(v >= n)) return;
        __builtin_amdgcn_s_sleep(1);
    }
}

// Counter barrier, ONLY for the end-of-kernel reset protocol.
__device__ __forceinline__ void gridbar(unsigned k, bool last) {
    __syncthreads();
    if (threadIdx.x == 0) {
        __threadfence();
        unsigned a = __hip_atomic_fetch_add(&g_cnt, 1u, __ATOMIC_ACQ_REL,
                                            __HIP_MEMORY_SCOPE_AGENT);
        if (a == k * NWG - 1u) {
            if (last) {
                __hip_atomic_store(&g_cnt, 0u, __ATOMIC_RELAXED, __HIP_MEMORY_SCOPE_AGENT);
                __hip_atomic_store(&g_gen, 0u, __ATOMIC_RELEASE, __HIP_MEMORY_SCOPE_AGENT);
            } else {
                __hip_atomic_store(&g_gen, k, __ATOMIC_RELEASE, __HIP_MEMORY_SCOPE_AGENT);
            }
        } else if (!last) {
            while (__hip_atomic_load(&g_gen, __ATOMIC_RELAXED,
                                     __HIP_MEMORY_SCOPE_AGENT) < k)
                __builtin_amdgcn_s_sleep(1);
        }
        __threadfence();
    }
    __syncthreads();
}

// One FMA block: 8 weight rows (2 j x 4 gates) x one k, two b columns.
#define STEPQ(Q, HA, HB)                                   \
    acc[0]  += w00.Q * (HA); acc[1]  += w00.Q * (HB);      \
    acc[2]  += w01.Q * (HA); acc[3]  += w01.Q * (HB);      \
    acc[4]  += w02.Q * (HA); acc[5]  += w02.Q * (HB);      \
    acc[6]  += w03.Q * (HA); acc[7]  += w03.Q * (HB);      \
    acc[8]  += w10.Q * (HA); acc[9]  += w10.Q * (HB);      \
    acc[10] += w11.Q * (HA); acc[11] += w11.Q * (HB);      \
    acc[12] += w12.Q * (HA); acc[13] += w12.Q * (HB);      \
    acc[14] += w13.Q * (HA); acc[15] += w13.Q * (HB);

#define LOADW(W, K, kk)                                                        \
    float4 w00 = *(const float4*)((W) + (size_t)(0 * NH + j0    ) * (K) + (kk)); \
    float4 w01 = *(const float4*)((W) + (size_t)(1 * NH + j0    ) * (K) + (kk)); \
    float4 w02 = *(const float4*)((W) + (size_t)(2 * NH + j0    ) * (K) + (kk)); \
    float4 w03 = *(const float4*)((W) + (size_t)(3 * NH + j0    ) * (K) + (kk)); \
    float4 w10 = *(const float4*)((W) + (size_t)(0 * NH + j0 + 1) * (K) + (kk)); \
    float4 w11 = *(const float4*)((W) + (size_t)(1 * NH + j0 + 1) * (K) + (kk)); \
    float4 w12 = *(const float4*)((W) + (size_t)(2 * NH + j0 + 1) * (K) + (kk)); \
    float4 w13 = *(const float4*)((W) + (size_t)(3 * NH + j0 + 1) * (K) + (kk));

// Partial dot over a 32-long k slice of bf16 h packed [k/2][b][2].
// One dwordx2 = 2 k x 2 b. Weights fp32, L1-resident, wave-uniform rows.
// (R0-verified inner form: unroll 4, per-iteration ldq.)
__device__ __forceinline__ void partH32(const float* __restrict__ W, int j0,
                                        int kbase,
                                        const unsigned* __restrict__ hd,
                                        int lane, float* acc) {
    const unsigned* hp = hd + (size_t)(kbase >> 1) * NB + (lane << 1);
    #pragma unroll 4
    for (int i = 0; i < 8; ++i) {
        const int kk = kbase + (i << 2);
        LOADW(W, NH, kk)
        unsigned long long q0 = ldq(hp + (size_t)(2 * i) * NB);
        unsigned long long q1 = ldq(hp + (size_t)(2 * i + 1) * NB);
        unsigned d00 = (unsigned)q0, d01 = (unsigned)(q0 >> 32);
        unsigned d10 = (unsigned)q1, d11 = (unsigned)(q1 >> 32);
        STEPQ(x, asfl(d00 << 16),          asfl(d01 << 16))
        STEPQ(y, asfl(d00 & 0xffff0000u),  asfl(d01 & 0xffff0000u))
        STEPQ(z, asfl(d10 << 16),          asfl(d11 << 16))
        STEPQ(w, asfl(d10 & 0xffff0000u),  asfl(d11 & 0xffff0000u))
    }
}

// Partial dot over an 8-long k slice of x stored [b][k] fp32 (cached loads).
__device__ __forceinline__ void partX8(const float* __restrict__ W, int j0,
                                       int k0, const float* __restrict__ xp,
                                       int lane, float* acc) {
    #pragma unroll
    for (int i4 = 0; i4 < 2; ++i4) {
        const int kk = k0 + (i4 << 2);
        LOADW(W, NI, kk)
        float4 xa = *(const float4*)(xp + (size_t)(lane << 1) * NI + kk);
        float4 xb = *(const float4*)(xp + (size_t)((lane << 1) + 1) * NI + kk);
        STEPQ(x, xa.x, xb.x)
        STEPQ(y, xa.y, xb.y)
        STEPQ(z, xa.z, xb.z)
        STEPQ(w, xa.w, xb.w)
    }
}

// Grid: 256 WGs x 512 thr, 1 WG/CU. gid<128: layer 0 (+head), else layer 1.
// WG g owns j0=2g, 2g+1 (8 gate rows) x all 128 b.
// PHASE-SPLIT step (this round's change): every wave accumulates BOTH
// matvec halves into one acc. Phase A (stale operand, no chain wait):
// Wih0·x (L0, k=wv*8 of 64) or Wih1·h0(t) (L1, k=wv*32 of 256). Then a
// SECOND gate for h(t-1), then phase B (chain): Whh·h(t-1), k=wv*32 —
// 512 FMA/lane with the stale work already retired, so the chain segment
// between h-publishes is half of R0's. Protocol/combine/LDS = R0 verbatim.
__global__ void __launch_bounds__(NTHR, 2) lstm2(
    const float* __restrict__ x,
    const float* __restrict__ h0in, const float* __restrict__ c0in,
    const float* __restrict__ Wih0, const float* __restrict__ Whh0,
    const float* __restrict__ bih0, const float* __restrict__ bhh0,
    const float* __restrict__ Wih1, const float* __restrict__ Whh1,
    const float* __restrict__ bih1, const float* __restrict__ bhh1,
    const float* __restrict__ Wlin, const float* __restrict__ blin,
    float* __restrict__ out,
    unsigned* __restrict__ h0d, unsigned* __restrict__ h1d)
{
    __shared__ __align__(16) float4 zp4[16 * NB];   // [wv*2+jl][b] fused partials
    __shared__ float red[4];
    __shared__ unsigned go_w;

    const int tid  = threadIdx.x;
    const int gid  = blockIdx.x;
    const bool is1 = gid >= NGRP;
    const int g    = is1 ? gid - NGRP : gid;
    const int j0   = g * 2;
    const int lane = tid & 63;
    const int wv   = __builtin_amdgcn_readfirstlane(tid >> 6);

    unsigned* ownc = is1 ? &g_c[32] : &g_c[0];

    // ---- init: biases + c state + h(-1) publish (packed bf16) ----
    float4 bsA = make_float4(0, 0, 0, 0), bsB = bsA;
    float cA = 0.f, cB = 0.f;
    if (tid < 128) {
        const float* bi = is1 ? bih1 : bih0;
        const float* bh = is1 ? bhh1 : bhh0;
        bsA.x = bi[0 * NH + j0] + bh[0 * NH + j0];
        bsA.y = bi[1 * NH + j0] + bh[1 * NH + j0];
        bsA.z = bi[2 * NH + j0] + bh[2 * NH + j0];
        bsA.w = bi[3 * NH + j0] + bh[3 * NH + j0];
        bsB.x = bi[0 * NH + j0 + 1] + bh[0 * NH + j0 + 1];
        bsB.y = bi[1 * NH + j0 + 1] + bh[1 * NH + j0 + 1];
        bsB.z = bi[2 * NH + j0 + 1] + bh[2 * NH + j0 + 1];
        bsB.w = bi[3 * NH + j0 + 1] + bh[3 * NH + j0 + 1];
        const float* cbase = c0in + (is1 ? 1 : 0) * NB * NH + (size_t)tid * NH + j0;
        cA = cbase[0]; cB = cbase[1];
        const float* hbase = h0in + (is1 ? 1 : 0) * NB * NH + (size_t)tid * NH + j0;
        unsigned d = (f2bf(hbase[1]) << 16) | f2bf(hbase[0]);
        unsigned* hT = is1 ? h1d : h0d;
        const int islot = is1 ? (R1 - 1) : (R0 - 1);
        std_(hT + (size_t)islot * SLOT + (size_t)g * NB + tid, d);
    }
    if (tid == 0) go_w = 0;
    const float blv = blin[0];
    asm volatile("s_waitcnt vmcnt(0)" ::: "memory");
    __syncthreads();
    if (tid == 0) bump(ownc);   // counters reach 128 per layer after init

    if (!is1) {
        // ================= layer 0 (+ head, lag HLAG) =================
        for (int s = 0; s < TT + HLAG; ++s) {
            const unsigned gA = 2u * (unsigned)s + 1u;
            const unsigned gB = gA + 1u;
            // Gate A: h0-ring store guard + head-data guard (L1 progress).
            if (wv == 0) {
                if (s >= R0) poll1(&g_c[32], 128u * (unsigned)(s - R0 + 2));
                if (lane == 0)
                    __hip_atomic_store(&go_w, gA, __ATOMIC_RELAXED,
                                       __HIP_MEMORY_SCOPE_WORKGROUP);
            } else {
                while (__hip_atomic_load(&go_w, __ATOMIC_RELAXED,
                                         __HIP_MEMORY_SCOPE_WORKGROUP) < gA) {}
            }

            float acc[16] = {0,0,0,0,0,0,0,0,0,0,0,0,0,0,0,0};
            if (s < TT)   // phase A: Wih0·x(s), k = wv*8 of 64 (no data wait)
                partX8(Wih0, j0, wv * 8, x + (size_t)s * NB * NI, lane, acc);

            if (s >= HLAG && tid >= 256) {          // head partial for u = s-HLAG
                const int u = s - HLAG;
                const int k = tid - 256;
                unsigned d = ldd(h1d + (size_t)(u & (R1 - 1)) * SLOT
                                 + (size_t)(k >> 1) * NB + g);
                float hv = (k & 1) ? asfl(d & 0xffff0000u) : asfl(d << 16);
                float p = Wlin[k] * hv;
                #pragma unroll
                for (int off = 32; off; off >>= 1) p += __shfl_down(p, off);
                if (lane == 0) red[wv - 4] = p;
            }

            if (s < TT) {
                // Gate B: h0(s-1) complete (the layer-0 chain).
                if (wv == 0) {
                    poll1(&g_c[0], 128u * (unsigned)(s + 1));
                    if (lane == 0)
                        __hip_atomic_store(&go_w, gB, __ATOMIC_RELAXED,
                                           __HIP_MEMORY_SCOPE_WORKGROUP);
                } else {
                    while (__hip_atomic_load(&go_w, __ATOMIC_RELAXED,
                                             __HIP_MEMORY_SCOPE_WORKGROUP) < gB) {}
                }
                // phase B: Whh0·h0(s-1), k = wv*32 of 256 (chain segment)
                partH32(Whh0, j0, wv * 32,
                        h0d + (size_t)((s + R0 - 1) & (R0 - 1)) * SLOT, lane, acc);
                const int base0 = ((wv << 1) + 0) * NB + (lane << 1);
                const int base1 = ((wv << 1) + 1) * NB + (lane << 1);
                zp4[base0]     = make_float4(acc[0],  acc[2],  acc[4],  acc[6]);
                zp4[base0 + 1] = make_float4(acc[1],  acc[3],  acc[5],  acc[7]);
                zp4[base1]     = make_float4(acc[8],  acc[10], acc[12], acc[14]);
                zp4[base1 + 1] = make_float4(acc[9],  acc[11], acc[13], acc[15]);
            }
            __syncthreads();

            if (s < TT && tid < 128) {              // combine both j, store packed
                float4 zA = bsA, zB = bsB;
                #pragma unroll
                for (int q = 0; q < 8; ++q) {
                    float4 a = zp4[(q * 2 + 0) * NB + tid];
                    float4 b = zp4[(q * 2 + 1) * NB + tid];
                    zA.x += a.x; zA.y += a.y; zA.z += a.z; zA.w += a.w;
                    zB.x += b.x; zB.y += b.y; zB.z += b.z; zB.w += b.w;
                }
                float iA = sigm(zA.x), fA = sigm(zA.y), gA2 = tanhfast(zA.z), oA = sigm(zA.w);
                cA = fA * cA + iA * gA2;
                float hA = oA * tanhfast(cA);
                float iB = sigm(zB.x), fB = sigm(zB.y), gB2 = tanhfast(zB.z), oB = sigm(zB.w);
                cB = fB * cB + iB * gB2;
                float hB = oB * tanhfast(cB);
                unsigned d = (f2bf(hB) << 16) | f2bf(hA);
                std_(h0d + (size_t)(s & (R0 - 1)) * SLOT + (size_t)g * NB + tid, d);
            }
            if (s >= HLAG && tid == 256)
                out[(size_t)(s - HLAG) * NB + g] = red[0] + red[1] + red[2] + red[3] + blv;

            asm volatile("s_waitcnt vmcnt(0)" ::: "memory");
            __syncthreads();
            if (s < TT && tid == 0) bump(&g_c[0]);
        }
    } else {
        // ================= layer 1 =================
        for (int t = 0; t < TT; ++t) {
            const unsigned gA = 2u * (unsigned)t + 1u;
            const unsigned gB = gA + 1u;
            // Gate A: h0(t) complete (stale — L0 runs ~7 ahead, rarely spins).
            if (wv == 0) {
                poll1(&g_c[0], 128u * (unsigned)(t + 2));
                if (lane == 0)
                    __hip_atomic_store(&go_w, gA, __ATOMIC_RELAXED,
                                       __HIP_MEMORY_SCOPE_WORKGROUP);
            } else {
                while (__hip_atomic_load(&go_w, __ATOMIC_RELAXED,
                                         __HIP_MEMORY_SCOPE_WORKGROUP) < gA) {}
            }

            float acc[16] = {0,0,0,0,0,0,0,0,0,0,0,0,0,0,0,0};
            // phase A: Wih1·h0(t), k = wv*32 of 256 (off-chain)
            partH32(Wih1, j0, wv * 32,
                    h0d + (size_t)(t & (R0 - 1)) * SLOT, lane, acc);

            // Gate B: h1(t-1) complete (the cross-step chain).
            if (wv == 0) {
                poll1(&g_c[32], 128u * (unsigned)(t + 1));
                if (lane == 0)
                    __hip_atomic_store(&go_w, gB, __ATOMIC_RELAXED,
                                       __HIP_MEMORY_SCOPE_WORKGROUP);
            } else {
                while (__hip_atomic_load(&go_w, __ATOMIC_RELAXED,
                                         __HIP_MEMORY_SCOPE_WORKGROUP) < gB) {}
            }
            // phase B: Whh1·h1(t-1), k = wv*32 of 256 (chain segment)
            partH32(Whh1, j0, wv * 32,
                    h1d + (size_t)((t + R1 - 1) & (R1 - 1)) * SLOT, lane, acc);
            const int base0 = ((wv << 1) + 0) * NB + (lane << 1);
            const int base1 = ((wv << 1) + 1) * NB + (lane << 1);
            zp4[base0]     = make_float4(acc[0],  acc[2],  acc[4],  acc[6]);
            zp4[base0 + 1] = make_float4(acc[1],  acc[3],  acc[5],  acc[7]);
            zp4[base1]     = make_float4(acc[8],  acc[10], acc[12], acc[14]);
            zp4[base1 + 1] = make_float4(acc[9],  acc[11], acc[13], acc[15]);
            __syncthreads();

            if (tid < 128) {
                float4 zA = bsA, zB = bsB;
                #pragma unroll
                for (int q = 0; q < 8; ++q) {
                    float4 a = zp4[(q * 2 + 0) * NB + tid];
                    float4 b = zp4[(q * 2 + 1) * NB + tid];
                    zA.x += a.x; zA.y += a.y; zA.z += a.z; zA.w += a.w;
                    zB.x += b.x; zB.y += b.y; zB.z += b.z; zB.w += b.w;
                }
                float iA = sigm(zA.x), fA = sigm(zA.y), gA2 = tanhfast(zA.z), oA = sigm(zA.w);
                cA = fA * cA + iA * gA2;
                float hA = oA * tanhfast(cA);
                float iB = sigm(zB.x), fB = sigm(zB.y), gB2 = tanhfast(zB.z), oB = sigm(zB.w);
                cB = fB * cB + iB * gB2;
                float hB = oB * tanhfast(cB);
                unsigned d = (f2bf(hB) << 16) | f2bf(hA);
                std_(h1d + (size_t)(t & (R1 - 1)) * SLOT + (size_t)g * NB + tid, d);
            }
            asm volatile("s_waitcnt vmcnt(0)" ::: "memory");
            __syncthreads();
            if (tid == 0) bump(&g_c[32]);
        }
    }

    // ---- end protocol: reset counters behind a real barrier (replay-safe) ----
    gridbar(1, false);
    if (gid == 0 && tid == 0) {
        __hip_atomic_store(&g_c[0],  0u, __ATOMIC_RELAXED, __HIP_MEMORY_SCOPE_AGENT);
        __hip_atomic_store(&g_c[32], 0u, __ATOMIC_RELAXED, __HIP_MEMORY_SCOPE_AGENT);
    }
    gridbar(2, true);
}

extern "C" void kernel_launch(void* const* d_in, const int* in_sizes, int n_in,
                              void* d_out, int out_size, void* d_ws, size_t ws_size,
                              hipStream_t stream)
{
    const float* x    = (const float*)d_in[0];
    const float* h0in = (const float*)d_in[1];
    const float* c0in = (const float*)d_in[2];
    const float* Wih0 = (const float*)d_in[3];
    const float* Whh0 = (const float*)d_in[4];
    const float* bih0 = (const float*)d_in[5];
    const float* bhh0 = (const float*)d_in[6];
    const float* Wih1 = (const float*)d_in[7];
    const float* Whh1 = (const float*)d_in[8];
    const float* bih1 = (const float*)d_in[9];
    const float* bhh1 = (const float*)d_in[10];
    const float* Wlin = (const float*)d_in[11];
    const float* blin = (const float*)d_in[12];
    float* out = (float*)d_out;

    unsigned* h0d = (unsigned*)d_ws;            // [R0][NH/2][NB] packed bf16
    unsigned* h1d = h0d + (size_t)R0 * SLOT;    // [R1][NH/2][NB] packed bf16

    void* args[] = { &x, &h0in, &c0in, &Wih0, &Whh0, &bih0, &bhh0,
                     &Wih1, &Whh1, &bih1, &bhh1, &Wlin, &blin,
                     &out, &h0d, &h1d };
    hipLaunchCooperativeKernel((void*)lstm2, dim3(NWG), dim3(NTHR), args, 0, stream);
}